// Round 1
// baseline (200.711 us; speedup 1.0000x reference)
//
#include <hip/hip_runtime.h>
#include <math.h>

// Problem constants (reference: N=64, H=512, W=512, RATIO=2, ITERATIONS=1)
#define NIMG 64
#define HH 512
#define WW 512
#define TR 8                           // output rows per wave-strip
#define SPI (HH / TR)                  // 64 strips per image
#define NSTRIP (NIMG * SPI)            // 4096 wave-strips
#define WPB 4                          // waves per block (256 threads)
#define NBLK (NSTRIP / WPB)            // 1024 blocks
#define INV_TOTAL (1.0f / 16777216.0f) // 1/(64*512*512), exact pow2

typedef unsigned int u32;
typedef unsigned long long u64;

// Flag byte per pixel: bit0 = (y>0), bit1 = (y==0), 0x00 = invalid row.
// cv2-clipped-border morphology: border = has_one & has_zero over the valid
// 3x3 window; invalid (out-of-image) cells contribute to NEITHER bit.
__device__ __forceinline__ u64 pack8(const int4 a, const int4 b) {
    u32 lo = ((a.x > 0) ? 1u : 2u)
           | (((a.y > 0) ? 1u : 2u) << 8)
           | (((a.z > 0) ? 1u : 2u) << 16)
           | (((a.w > 0) ? 1u : 2u) << 24);
    u32 hi = ((b.x > 0) ? 1u : 2u)
           | (((b.y > 0) ? 1u : 2u) << 8)
           | (((b.z > 0) ? 1u : 2u) << 16)
           | (((b.w > 0) ? 1u : 2u) << 24);
    return (u64)lo | ((u64)hi << 32);
}

// Horizontal 3-OR of flag bytes; cross-lane edge bytes via wave shuffles.
// h[i] = f[i-1] | f[i] | f[i+1], with col -1 / col 512 contributing 0.
// Row validity is wave-uniform, so an invalid row passes f==0 for all lanes
// and the shuffles correctly propagate zeros.
__device__ __forceinline__ u64 hor3(u64 f, int lane) {
    const u32 hi = (u32)(f >> 32);
    const u32 lo = (u32)f;
    const u32 lw = __shfl_up(hi, 1);    // left neighbor's high word
    const u32 rw = __shfl_down(lo, 1);  // right neighbor's low word
    const u64 left  = (lane == 0)  ? 0ull : (u64)(lw >> 24);          // col 8c-1
    const u64 right = (lane == 63) ? 0ull : ((u64)(rw & 0xffu) << 56); // col 8c+8
    return f | (f << 8) | (f >> 8) | left | right;
}

// Barrier-free rolling-register kernel: each wave walks an 8-row strip,
// keeping the 3-row vertical window in registers. 2-deep software pipeline:
// y/x loads for row r+1 are issued one full iteration before consumption.
__global__ __launch_bounds__(256, 4) void border_loss_main(
    const float* __restrict__ x, const int* __restrict__ y,
    float* __restrict__ part, int atomic_mode)
{
    __shared__ float wsum[WPB];

    const int tid  = threadIdx.x;
    const int lane = tid & 63;
    const int wv   = tid >> 6;
    const int s    = blockIdx.x * WPB + wv;   // wave-strip id
    const int n    = s >> 6;                  // image (SPI = 64 strips/image)
    const int R0   = (s & (SPI - 1)) * TR;    // first output row of strip
    const int base = n * (HH * WW);           // < 2^24, int-safe
    const int*   __restrict__ yp = y + base + (lane << 3);
    const float* __restrict__ xp = x + base + (lane << 3);

    // ---- prologue: flags for rows R0-1 and R0; raw y for row R0+1; x row R0
    u64 f_a;
    if (R0 > 0) {
        const int4* p = (const int4*)(yp + (R0 - 1) * WW);
        f_a = pack8(p[0], p[1]);
    } else {
        f_a = 0ull;                           // clipped top border
    }
    u64 h_a = hor3(f_a, lane);

    u64 f_b;
    {
        const int4* p = (const int4*)(yp + R0 * WW);
        f_b = pack8(p[0], p[1]);
    }
    u64 h_b = hor3(f_b, lane);

    int4 yc0, yc1;                            // y row R0+r+1 (in flight)
    bool vc = true;                           // R0+1 <= 505 < HH always
    {
        const int4* p = (const int4*)(yp + (R0 + 1) * WW);
        yc0 = p[0]; yc1 = p[1];
    }
    float4 xc0, xc1;                          // x row R0+r (in flight)
    {
        const float4* p = (const float4*)(xp + R0 * WW);
        xc0 = p[0]; xc1 = p[1];
    }

    float acc = 0.0f;
    #pragma unroll
    for (int r = 0; r < TR; ++r) {
        // ---- issue next iteration's loads FIRST (consumed next iteration)
        int4 yn0, yn1; bool vn = false;
        float4 xn0, xn1;
        if (r < TR - 1) {                     // compile-time after unroll
            const int g = R0 + r + 2;
            vn = (g < HH);                    // wave-uniform guard (bottom clip)
            if (vn) {
                const int4* p = (const int4*)(yp + g * WW);
                yn0 = p[0]; yn1 = p[1];
            } else {
                yn0 = make_int4(0, 0, 0, 0); yn1 = make_int4(0, 0, 0, 0);
            }
            const float4* p = (const float4*)(xp + (R0 + r + 1) * WW);
            xn0 = p[0]; xn1 = p[1];
        } else {                              // dead after unroll (DCE)
            yn0 = make_int4(0, 0, 0, 0); yn1 = make_int4(0, 0, 0, 0);
            xn0 = make_float4(0.f, 0.f, 0.f, 0.f);
            xn1 = make_float4(0.f, 0.f, 0.f, 0.f);
        }

        // ---- flags/h for row R0+r+1 from y loaded a full iteration ago
        const u64 f_c = vc ? pack8(yc0, yc1) : 0ull;
        const u64 h_c = hor3(f_c, lane);

        // ---- 3x3 morphology: vertical OR, then border = has_one & has_zero
        const u64 v      = h_a | h_b | h_c;
        const u64 border = v & (v >> 1) & 0x0101010101010101ull;
        const u64 m64    = f_b;               // center-row m bits (bit0/byte)

        // ---- per-pixel: max(x,0) - x*m + ln(1+e^{-|x|}); weight 2 on border
        #define PX(XF, K) { \
            const float xf = (XF); \
            const float lg = __logf(1.0f + __expf(-fabsf(xf))); \
            const float ls = fmaxf(xf, 0.0f) \
                           - (((m64 >> (K)) & 1ull) ? xf : 0.0f) + lg; \
            acc = fmaf(ls, ((border >> (K)) & 1ull) ? 2.0f : 1.0f, acc); }
        PX(xc0.x,  0) PX(xc0.y,  8) PX(xc0.z, 16) PX(xc0.w, 24)
        PX(xc1.x, 32) PX(xc1.y, 40) PX(xc1.z, 48) PX(xc1.w, 56)
        #undef PX

        // ---- rotate the pipeline
        h_a = h_b; h_b = h_c; f_b = f_c;
        yc0 = yn0; yc1 = yn1; vc = vn;
        xc0 = xn0; xc1 = xn1;
    }

    // ---- reduction: wave shuffle + tiny LDS across 4 waves
    #pragma unroll
    for (int off = 32; off > 0; off >>= 1)
        acc += __shfl_down(acc, off);
    if (lane == 0) wsum[wv] = acc;
    __syncthreads();
    if (tid == 0) {
        const float t = wsum[0] + wsum[1] + wsum[2] + wsum[3];
        if (atomic_mode) atomicAdd(part, t * INV_TOTAL);
        else             part[blockIdx.x] = t;
    }
}

__global__ __launch_bounds__(256) void border_loss_reduce(
    const float* __restrict__ part, float* __restrict__ out)
{
    __shared__ float wsum[4];
    float t = 0.0f;
    for (int i = threadIdx.x; i < NBLK; i += 256) t += part[i];
    #pragma unroll
    for (int off = 32; off > 0; off >>= 1)
        t += __shfl_down(t, off);
    if ((threadIdx.x & 63) == 0) wsum[threadIdx.x >> 6] = t;
    __syncthreads();
    if (threadIdx.x == 0)
        out[0] = (wsum[0] + wsum[1] + wsum[2] + wsum[3]) * INV_TOTAL;
}

__global__ void border_loss_zero(float* out) { out[0] = 0.0f; }

extern "C" void kernel_launch(void* const* d_in, const int* in_sizes, int n_in,
                              void* d_out, int out_size, void* d_ws, size_t ws_size,
                              hipStream_t stream)
{
    const float* x = (const float*)d_in[0];
    const int*   y = (const int*)d_in[1];
    float* out = (float*)d_out;

    if (ws_size >= (size_t)NBLK * sizeof(float)) {
        // Deterministic two-stage reduction via workspace partials.
        float* part = (float*)d_ws;
        border_loss_main<<<NBLK, 256, 0, stream>>>(x, y, part, 0);
        border_loss_reduce<<<1, 256, 0, stream>>>(part, out);
    } else {
        // Fallback: zero output then atomic accumulation.
        border_loss_zero<<<1, 1, 0, stream>>>(out);
        border_loss_main<<<NBLK, 256, 0, stream>>>(x, y, out, 1);
    }
}

// Round 2
// 147.980 us; speedup vs baseline: 1.3563x; 1.3563x over previous
//
#include <hip/hip_runtime.h>
#include <math.h>

// Problem constants (reference: N=64, H=512, W=512, RATIO=2, ITERATIONS=1)
#define NIMG 64
#define HH 512
#define WW 512
#define TR 4                           // output rows per wave-strip
#define SPI (HH / TR)                  // 128 strips per image
#define NSTRIP (NIMG * SPI)            // 8192 wave-strips
#define WPB 4                          // waves per block (256 threads)
#define NBLK (NSTRIP / WPB)            // 2048 blocks -> 8 blocks/CU, 32 waves/CU
#define INV_TOTAL (1.0f / 16777216.0f) // 1/(64*512*512), exact pow2

typedef unsigned int u32;
typedef unsigned long long u64;

// Flag byte per pixel: bit0 = (y>0), bit1 = (y==0), 0x00 = invalid row.
// cv2-clipped-border morphology: border = has_one & has_zero over the valid
// 3x3 window; invalid (out-of-image) cells contribute to NEITHER bit.
__device__ __forceinline__ u64 pack8(const int4 a, const int4 b) {
    u32 lo = ((a.x > 0) ? 1u : 2u)
           | (((a.y > 0) ? 1u : 2u) << 8)
           | (((a.z > 0) ? 1u : 2u) << 16)
           | (((a.w > 0) ? 1u : 2u) << 24);
    u32 hi = ((b.x > 0) ? 1u : 2u)
           | (((b.y > 0) ? 1u : 2u) << 8)
           | (((b.z > 0) ? 1u : 2u) << 16)
           | (((b.w > 0) ? 1u : 2u) << 24);
    return (u64)lo | ((u64)hi << 32);
}

// Horizontal 3-OR of flag bytes; cross-lane edge bytes via wave shuffles.
// h[i] = f[i-1] | f[i] | f[i+1], with col -1 / col 512 contributing 0.
__device__ __forceinline__ u64 hor3(u64 f, int lane) {
    const u32 hi = (u32)(f >> 32);
    const u32 lo = (u32)f;
    const u32 lw = __shfl_up(hi, 1);    // left neighbor's high word
    const u32 rw = __shfl_down(lo, 1);  // right neighbor's low word
    const u64 left  = (lane == 0)  ? 0ull : (u64)(lw >> 24);           // col 8c-1
    const u64 right = (lane == 63) ? 0ull : ((u64)(rw & 0xffu) << 56); // col 8c+8
    return f | (f << 8) | (f >> 8) | left | right;
}

// Barrier-free rolling-register kernel: each wave walks a 4-row strip with a
// 1-iteration-deep software pipeline. #pragma unroll 1 keeps the pipeline
// exactly as written (round-1 lesson: full unroll -> load hoisting -> spills).
__global__ __launch_bounds__(256, 8) void border_loss_main(
    const float* __restrict__ x, const int* __restrict__ y,
    float* __restrict__ part, int atomic_mode)
{
    __shared__ float wsum[WPB];

    const int tid  = threadIdx.x;
    const int lane = tid & 63;
    const int wv   = tid >> 6;
    const int s    = blockIdx.x * WPB + wv;   // wave-strip id
    const int n    = s >> 7;                  // image (SPI = 128 strips/image)
    const int R0   = (s & (SPI - 1)) * TR;    // first output row of strip
    const int base = n * (HH * WW);           // < 2^24, int-safe
    const int*   __restrict__ yp = y + base + (lane << 3);
    const float* __restrict__ xp = x + base + (lane << 3);

    // ---- prologue: h for rows R0-1, R0; raw y row R0+1; x row R0
    u64 h_a;
    if (R0 > 0) {
        const int4* p = (const int4*)(yp + (R0 - 1) * WW);
        h_a = hor3(pack8(p[0], p[1]), lane);
    } else {
        h_a = 0ull;                           // clipped top border
    }
    u64 f_b, h_b;
    {
        const int4* p = (const int4*)(yp + R0 * WW);
        f_b = pack8(p[0], p[1]);
        h_b = hor3(f_b, lane);
    }
    int4 yc0, yc1;                            // raw y row R0+r+1 (in flight)
    {
        const int4* p = (const int4*)(yp + (R0 + 1) * WW);  // R0+1 <= 509, valid
        yc0 = p[0]; yc1 = p[1];
    }
    float4 xc0, xc1;                          // x row R0+r (in flight)
    {
        const float4* p = (const float4*)(xp + R0 * WW);
        xc0 = p[0]; xc1 = p[1];
    }
    u64 mc = ~0ull;                           // validity mask of yc's row

    // per-pixel: max(x,0) - x*m + ln(1+e^{-|x|}); weight 2 on border
    #define PX(XF, K) { \
        const float xf = (XF); \
        const float lg = __logf(1.0f + __expf(-fabsf(xf))); \
        const float ls = fmaxf(xf, 0.0f) \
                       - (((m64 >> (K)) & 1ull) ? xf : 0.0f) + lg; \
        acc = fmaf(ls, ((border >> (K)) & 1ull) ? 2.0f : 1.0f, acc); }

    float acc = 0.0f;
    #pragma unroll 1
    for (int r = 0; r < TR - 1; ++r) {
        // flags/h for row R0+r+1 (r <= TR-2 -> row <= 511, always valid)
        const u64 f_c = pack8(yc0, yc1);
        const u64 h_c = hor3(f_c, lane);

        // ---- prefetch next iteration's y (row R0+r+2) and x (row R0+r+1)
        const int gn  = R0 + r + 2;
        const int gcl = (gn < HH) ? gn : (HH - 1);   // clamp; mask kills flags
        mc = (gn < HH) ? ~0ull : 0ull;
        const int4* pn = (const int4*)(yp + gcl * WW);
        const int4 yn0 = pn[0], yn1 = pn[1];
        const float4* px = (const float4*)(xp + (R0 + r + 1) * WW);
        const float4 xn0 = px[0], xn1 = px[1];

        // ---- 3x3 morphology + loss for output row R0+r
        const u64 v      = h_a | h_b | h_c;
        const u64 border = v & (v >> 1) & 0x0101010101010101ull;
        const u64 m64    = f_b;               // center-row m bits (bit0/byte)
        PX(xc0.x,  0) PX(xc0.y,  8) PX(xc0.z, 16) PX(xc0.w, 24)
        PX(xc1.x, 32) PX(xc1.y, 40) PX(xc1.z, 48) PX(xc1.w, 56)

        // ---- rotate the pipeline
        h_a = h_b; h_b = h_c; f_b = f_c;
        yc0 = yn0; yc1 = yn1;
        xc0 = xn0; xc1 = xn1;
    }
    // ---- peeled last row (R0+TR-1): yc holds row R0+TR, masked if == HH
    {
        const u64 f_c = pack8(yc0, yc1) & mc;
        const u64 h_c = hor3(f_c, lane);
        const u64 v      = h_a | h_b | h_c;
        const u64 border = v & (v >> 1) & 0x0101010101010101ull;
        const u64 m64    = f_b;
        PX(xc0.x,  0) PX(xc0.y,  8) PX(xc0.z, 16) PX(xc0.w, 24)
        PX(xc1.x, 32) PX(xc1.y, 40) PX(xc1.z, 48) PX(xc1.w, 56)
    }
    #undef PX

    // ---- reduction: wave shuffle + tiny LDS across 4 waves
    #pragma unroll
    for (int off = 32; off > 0; off >>= 1)
        acc += __shfl_down(acc, off);
    if (lane == 0) wsum[wv] = acc;
    __syncthreads();
    if (tid == 0) {
        const float t = wsum[0] + wsum[1] + wsum[2] + wsum[3];
        if (atomic_mode) atomicAdd(part, t * INV_TOTAL);
        else             part[blockIdx.x] = t;
    }
}

__global__ __launch_bounds__(256) void border_loss_reduce(
    const float* __restrict__ part, float* __restrict__ out)
{
    __shared__ float wsum[4];
    float t = 0.0f;
    for (int i = threadIdx.x; i < NBLK; i += 256) t += part[i];
    #pragma unroll
    for (int off = 32; off > 0; off >>= 1)
        t += __shfl_down(t, off);
    if ((threadIdx.x & 63) == 0) wsum[threadIdx.x >> 6] = t;
    __syncthreads();
    if (threadIdx.x == 0)
        out[0] = (wsum[0] + wsum[1] + wsum[2] + wsum[3]) * INV_TOTAL;
}

__global__ void border_loss_zero(float* out) { out[0] = 0.0f; }

extern "C" void kernel_launch(void* const* d_in, const int* in_sizes, int n_in,
                              void* d_out, int out_size, void* d_ws, size_t ws_size,
                              hipStream_t stream)
{
    const float* x = (const float*)d_in[0];
    const int*   y = (const int*)d_in[1];
    float* out = (float*)d_out;

    if (ws_size >= (size_t)NBLK * sizeof(float)) {
        // Deterministic two-stage reduction via workspace partials.
        float* part = (float*)d_ws;
        border_loss_main<<<NBLK, 256, 0, stream>>>(x, y, part, 0);
        border_loss_reduce<<<1, 256, 0, stream>>>(part, out);
    } else {
        // Fallback: zero output then atomic accumulation.
        border_loss_zero<<<1, 1, 0, stream>>>(out);
        border_loss_main<<<NBLK, 256, 0, stream>>>(x, y, out, 1);
    }
}